// Round 1
// 173.801 us; speedup vs baseline: 1.1217x; 1.1217x over previous
//
#include <hip/hip_runtime.h>
#include <stdint.h>

#define NA 200000
#define NB 8
#define NM 64
#define APB 1024                // anchors per k_main block (4 per thread, register-blocked)
#define CPB 196                 // 196*1024 = 200704 >= 200000
#define NA4 50000               // NA/4 uint4 per image
#define SPB 128                 // scan blocks per image (k_h2c)
#define SEGCAP 25600            // per-(image,seg) cbuf capacity: exact worst-case bound
#define IMGCAP (8*SEGCAP)       // 204800 dwords per image

// ---- workspace layout (dword offsets) ----
// scal: 8 images x 16 slots: [0]np [1]nn [2]ps(f32) [3]bs(f32) [8..15] seg counters
#define O_SCAL 0
#define O_L1C  128                   // 8 x 256
#define O_L1S  2176
#define O_KEYS 4224                  // 8 x 200000 (byte 16896, 16B-aligned)
#define O_CBUF 1604224               // 8 x IMGCAP compacted keys (segmented)
#define N_ZERO 4224                  // zero scal + L1 only (16.9 KB)

__device__ __forceinline__ unsigned int f2key(float f) {
    unsigned int u = __float_as_uint(f);
    return (u & 0x80000000u) ? ~u : (u | 0x80000000u);
}
__device__ __forceinline__ float key2f(unsigned int k) {
    return (k & 0x80000000u) ? __uint_as_float(k & 0x7fffffffu) : __uint_as_float(~k);
}
__device__ __forceinline__ unsigned int calck(const unsigned int* scal, int b) {
    const unsigned int np = scal[b * 16], nn = scal[b * 16 + 1];
    if (!np) return 0u;
    const unsigned int kp = np * 3u;
    return (kp < nn) ? kp : nn;
}

// barrier-free select over a 256-bin (cnt,sum) histogram: one wave, 4 bins/lane. (r9-r12 verified)
__device__ __forceinline__ void wave_sel256(
    const unsigned int* __restrict__ cnt, const float* __restrict__ sum,
    unsigned int target, unsigned int* c, unsigned int* cab, float* sab)
{
    const int lane = (int)(threadIdx.x & 63u);
    const uint4  c4 = ((const uint4*)cnt)[lane];
    const float4 s4 = ((const float4*)sum)[lane];
    unsigned int S = c4.x + c4.y + c4.z + c4.w;
    float Sf = s4.x + s4.y + s4.z + s4.w;
    for (int d = 1; d < 64; d <<= 1) {           // inclusive suffix scan across lanes
        const unsigned int oc = __shfl_down(S, d);
        const float of = __shfl_down(Sf, d);
        if (lane + d < 64) { S += oc; Sf += of; }
    }
    unsigned int Sn = __shfl_down(S, 1);          // suffix strictly above this lane's bins
    float Sfn = __shfl_down(Sf, 1);
    if (lane == 63) { Sn = 0u; Sfn = 0.0f; }
    const unsigned int cb[4] = {c4.x, c4.y, c4.z, c4.w};
    const float sb[4] = {s4.x, s4.y, s4.z, s4.w};
    unsigned int run = Sn; float runs = Sfn;
    bool found = false; unsigned int lc = 0, lcab = 0; float lsab = 0.0f;
#pragma unroll
    for (int j = 3; j >= 0; --j) {
        const unsigned int prev = run; const float prevs = runs;
        run += cb[j]; runs += sb[j];
        if (run >= target && prev < target) {
            found = true; lc = (unsigned int)(4 * lane + j); lcab = prev; lsab = prevs;
        }
    }
    const unsigned long long m = __ballot(found);
    const int src = __ffsll((long long)m) - 1;
    *c = __shfl(lc, src); *cab = __shfl(lcab, src); *sab = __shfl(lsab, src);
}

// single-wave two-level select over a 4096-bin COUNT histogram in LDS. Zero barriers.
// Returns crossing bin and count strictly above it. target >= 1, total >= target.
__device__ __forceinline__ void wave_sel4096_cnt(
    const unsigned int* hc, unsigned int target, unsigned int* bin, unsigned int* cab)
{
    const int lane = (int)(threadIdx.x & 63u);
    unsigned int cs = 0;
    const uint4* p = (const uint4*)(hc + lane * 64);   // lane owns bins [64*lane, 64*lane+64)
#pragma unroll
    for (int j = 0; j < 16; ++j) { const uint4 u = p[j]; cs += u.x + u.y + u.z + u.w; }
    unsigned int S = cs;
    for (int d = 1; d < 64; d <<= 1) { const unsigned int o = __shfl_down(S, d); if (lane + d < 64) S += o; }
    unsigned int Sn = __shfl_down(S, 1); if (lane == 63) Sn = 0u;
    const bool f1 = (S >= target) && (Sn < target);    // unique crossing chunk
    const unsigned long long m1 = __ballot(f1);
    const int chunk = __ffsll((long long)m1) - 1;
    const unsigned int above = __shfl(Sn, chunk);
    unsigned int S2 = hc[chunk * 64 + lane];
    for (int d = 1; d < 64; d <<= 1) { const unsigned int o = __shfl_down(S2, d); if (lane + d < 64) S2 += o; }
    unsigned int S2n = __shfl_down(S2, 1); if (lane == 63) S2n = 0u;
    const bool f2 = (above + S2 >= target) && (above + S2n < target);
    const unsigned long long m2 = __ballot(f2);
    const int l2 = __ffsll((long long)m2) - 1;
    *bin = (unsigned int)(chunk * 64 + l2);
    *cab = above + __shfl(S2n, l2);
}

// one IoU pair + rational running-max update. fp contract OFF to match reference rounding.
__device__ __forceinline__ void iou_upd(
    const float4 Aq, const float aaq, const float4 B, const float abj, const int j,
    float& bi, float& bu, int& arg)
{
#pragma clang fp contract(off)
    const float iw = fmaxf(fminf(Aq.z, B.z) - fmaxf(Aq.x, B.x), 0.0f);
    const float ih = fmaxf(fminf(Aq.w, B.w) - fmaxf(Aq.y, B.y), 0.0f);
    const float inter = iw * ih;
    const float ua = fmaxf(aaq + abj - inter, 1e-8f);
    if (inter * bu > bi * ua) { bi = inter; bu = ua; arg = j; }
}

// per-anchor epilogue: key write + LDS L1 hist + pos-path box loss accumulation.
// cv is preloaded (hides global latency under the IoU loop). Math identical to r12.
__device__ __forceinline__ void epi2(
    int b, int i, float4 a4, int arg, bool pos, bool neg, float2 cv,
    const float* __restrict__ reg, const float4* sbox, unsigned int* __restrict__ keys,
    unsigned int* hc8, float* hs8, float& posv, float& boxv)
{
    unsigned int key = 0u;   // excluded anchors: key 0
    if (neg) {
        const float nl = -cv.y;
        key = f2key(nl);
        atomicAdd(&hc8[key >> 24], 1u);
        atomicAdd(&hs8[key >> 24], nl);
    }
    keys[(size_t)b * NA + i] = key;
    if (pos) {
        posv += -cv.x;
        const float4 g = sbox[arg];
        const float aw = a4.z - a4.x, ah = a4.w - a4.y;
        const float acx = a4.x + 0.5f * aw, acy = a4.y + 0.5f * ah;
        const float gw = g.z - g.x, gh = g.w - g.y;
        const float gcx = g.x + 0.5f * gw, gcy = g.y + 0.5f * gh;
        const float t0 = ((gcx - acx) / (aw + 1e-14f)) / 0.1f;
        const float t1 = ((gcy - acy) / (ah + 1e-14f)) / 0.1f;
        const float t2 = logf(gw / aw) / 0.2f;
        const float t3 = logf(gh / ah) / 0.2f;
        const float4 r = ((const float4*)reg)[(size_t)b * NA + i];
        const float d0 = fabsf(t0 - r.x);
        const float d1 = fabsf(t1 - r.y);
        const float d2 = fabsf(t2 - r.z);
        const float d3 = fabsf(t3 - r.w);
        const float l0 = (d0 < 1.0f) ? 0.5f * d0 * d0 : d0 - 0.5f;
        const float l1 = (d1 < 1.0f) ? 0.5f * d1 * d1 : d1 - 0.5f;
        const float l2 = (d2 < 1.0f) ? 0.5f * d2 * d2 : d2 - 0.5f;
        const float l3 = (d3 < 1.0f) ? 0.5f * d3 * d3 : d3 - 0.5f;
        boxv += l0 + l1 + l2 + l3;
    }
}

// ---------------- K1: register-blocked 4 anchors/thread x 4-box chunks --------------------
// r13 theory: VGPR=44 forced JIT LDS re-reads + 2-chain ILP -> lgkm stalls.
// 4x4 blocking holds all operands in regs (16 independent pairs/chunk, 4 max-chains),
// cls prefetched before the loop. Budget ~80-100 VGPR, under the (256,4) cap of 128.
__global__ __launch_bounds__(256, 4) void k_main(
    const float* __restrict__ cls, const float* __restrict__ reg,
    const float* __restrict__ anchors, const float* __restrict__ ann,
    unsigned int* __restrict__ scal, unsigned int* __restrict__ l1cnt,
    float* __restrict__ l1sum, unsigned int* __restrict__ keys)
{
    __shared__ float4 sbox[NM];          // compacted valid boxes + sentinels
    __shared__ unsigned int s_nv;
    __shared__ unsigned int hc8[256];
    __shared__ float hs8[256];
    __shared__ unsigned int s_np, s_nn;
    __shared__ float s_ps, s_bs;

    const int b = blockIdx.y;
    const int tid = threadIdx.x;
    const int ibase = blockIdx.x * APB + tid;

    // prefetch anchors + cls early: latency overlaps the box staging + barriers
    float4 A[4]; float2 CV[4];
#pragma unroll
    for (int q = 0; q < 4; ++q) {
        const int i = ibase + q * 256;
        if (i < NA) {
            A[q]  = ((const float4*)anchors)[i];
            CV[q] = ((const float2*)cls)[(size_t)b * NA + i];
        } else {
            A[q]  = make_float4(0.f, 0.f, 0.f, 0.f);
            CV[q] = make_float2(0.f, 0.f);
        }
    }

    if (tid < NM) {   // exactly wave 0
        const float4 bb = ((const float4*)ann)[b * NM + tid];
        const bool valid = (bb.x > 0.0f);
        const unsigned long long m = __ballot(valid);
        if (valid) {
            const int p = __popcll(m & ((1ull << (tid & 63)) - 1ull));
            sbox[p] = bb;
        }
        if (tid == 0) s_nv = (unsigned int)__popcll(m);
    }
    hc8[tid] = 0u; hs8[tid] = 0.0f;
    if (tid == 0) { s_np = 0u; s_nn = 0u; s_ps = 0.0f; s_bs = 0.0f; }
    __syncthreads();
    const int nv = (int)s_nv;
    const int nvr = (nv + 3) & ~3;       // round up to multiple of 4 (<= 64)
    if (tid >= nv && tid < nvr) {        // sentinel pad: inter=0, ua=inf -> can never win
        sbox[tid] = make_float4(__builtin_inff(), __builtin_inff(),
                                -__builtin_inff(), -__builtin_inff());
    }
    __syncthreads();

    float aa[4];
    {
#pragma clang fp contract(off)
#pragma unroll
        for (int q = 0; q < 4; ++q) aa[q] = (A[q].z - A[q].x) * (A[q].w - A[q].y);
    }
    float bi[4] = {-1.0f, -1.0f, -1.0f, -1.0f};
    float bu[4] = {1.0f, 1.0f, 1.0f, 1.0f};
    int arg[4] = {0, 0, 0, 0};

#pragma unroll 1
    for (int mo = 0; mo < nvr; mo += 4) {
        const float4 b0 = sbox[mo + 0];
        const float4 b1 = sbox[mo + 1];
        const float4 b2 = sbox[mo + 2];
        const float4 b3 = sbox[mo + 3];
        float ab0, ab1, ab2, ab3;
        {
#pragma clang fp contract(off)
            ab0 = (b0.z - b0.x) * (b0.w - b0.y);
            ab1 = (b1.z - b1.x) * (b1.w - b1.y);
            ab2 = (b2.z - b2.x) * (b2.w - b2.y);
            ab3 = (b3.z - b3.x) * (b3.w - b3.y);
        }
#pragma unroll
        for (int q = 0; q < 4; ++q) {
            iou_upd(A[q], aa[q], b0, ab0, mo + 0, bi[q], bu[q], arg[q]);
            iou_upd(A[q], aa[q], b1, ab1, mo + 1, bi[q], bu[q], arg[q]);
            iou_upd(A[q], aa[q], b2, ab2, mo + 2, bi[q], bu[q], arg[q]);
            iou_upd(A[q], aa[q], b3, ab3, mo + 3, bi[q], bu[q], arg[q]);
        }
    }

    bool pos[4], neg[4];
    {
#pragma clang fp contract(off)
#pragma unroll
        for (int q = 0; q < 4; ++q) {
            pos[q] = (bi[q] >= 0.5f * bu[q]);
            neg[q] = (bi[q] < 0.3f * bu[q]);
        }
    }

    float posv = 0.0f, boxv = 0.0f;
#pragma unroll
    for (int q = 0; q < 4; ++q) {
        const int i = ibase + q * 256;
        if (i < NA) {
            epi2(b, i, A[q], arg[q], pos[q], neg[q], CV[q], reg, sbox, keys, hc8, hs8, posv, boxv);
        } else { pos[q] = false; neg[q] = false; }
    }

    unsigned int pc = 0, nc = 0; bool anyp = false;
#pragma unroll
    for (int q = 0; q < 4; ++q) {
        const unsigned long long pb = __ballot(pos[q]);
        const unsigned long long nb = __ballot(neg[q]);
        anyp |= (pb != 0ull);
        pc += (unsigned int)__popcll(pb);
        nc += (unsigned int)__popcll(nb);
    }
    if (anyp) {
        for (int off = 32; off; off >>= 1) {
            posv += __shfl_xor(posv, off);
            boxv += __shfl_xor(boxv, off);
        }
    }
    if ((tid & 63) == 0) {
        if (nc) atomicAdd(&s_nn, nc);
        if (pc) { atomicAdd(&s_np, pc); atomicAdd(&s_ps, posv); atomicAdd(&s_bs, boxv); }
    }
    __syncthreads();
    unsigned int* sg = scal + b * 16;
    if (tid == 0) {
        if (s_nn) atomicAdd(&sg[1], s_nn);
        if (s_np) {
            atomicAdd(&sg[0], s_np);
            atomicAdd((float*)(sg + 2), s_ps);
            atomicAdd((float*)(sg + 3), s_bs);
        }
    }
    if (hc8[tid]) {
        atomicAdd(&l1cnt[b * 256 + tid], hc8[tid]);
        atomicAdd(&l1sum[b * 256 + tid], hs8[tid]);
    }
}

// ---------------- T1: UNCHANGED r12 segmented compaction (1 atomic/block, 8 ctrs/image) ------
__global__ __launch_bounds__(256) void k_h2c(
    const unsigned int* __restrict__ keys, unsigned int* __restrict__ scal,
    const unsigned int* __restrict__ l1c, const float* __restrict__ l1s,
    unsigned int* __restrict__ cbuf)
{
    __shared__ unsigned int wcnt[4];
    __shared__ unsigned int sbase;
    const int b = blockIdx.x >> 7;
    const int sub = blockIdx.x & (SPB - 1);
    const int tid = threadIdx.x;
    const unsigned int k = calck(scal, b);
    if (k == 0) return;   // grid-uniform per image
    unsigned int c1, cab1; float sab1;
    wave_sel256(l1c + b * 256, l1s + b * 256, k, &c1, &cab1, &sab1);   // barrier-free

    const uint4* kp4 = (const uint4*)(keys + (size_t)b * NA);
    const int j0 = sub * 256 + tid;          // [0, 32767] < NA4
    const int j1 = j0 + SPB * 256;           // [32768, 65535]
    const uint4 v0 = kp4[j0];
    const uint4 v1 = (j1 < NA4) ? kp4[j1] : make_uint4(0, 0, 0, 0);
    const unsigned int kk[8] = {v0.x, v0.y, v0.z, v0.w, v1.x, v1.y, v1.z, v1.w};

    const int lane = tid & 63;
    const int wave = tid >> 6;
    bool m[8];
    unsigned long long mask[8];
    unsigned int tot = 0;
#pragma unroll
    for (int j = 0; j < 8; ++j) {
        m[j] = kk[j] && (kk[j] >> 24) == c1;
        mask[j] = __ballot(m[j]);
        tot += (unsigned int)__popcll(mask[j]);
    }
    if (lane == 0) wcnt[wave] = tot;
    __syncthreads();
    if (tid == 0) {   // exclusive prefix over waves + ONE atomic per block
        unsigned int p = 0;
#pragma unroll
        for (int w = 0; w < 4; ++w) { const unsigned int t = wcnt[w]; wcnt[w] = p; p += t; }
        sbase = p ? atomicAdd(&scal[b * 16 + 8 + (sub & 7)], p) : 0u;
    }
    __syncthreads();
    unsigned int base = sbase + wcnt[wave];
    if (tot) {
        unsigned int* cb = cbuf + (size_t)b * IMGCAP + (sub & 7) * SEGCAP;
        const unsigned long long lt = (lane == 63) ? ~0ull >> 1 : ((1ull << (lane + 1)) - 1ull) >> 1;
#pragma unroll
        for (int j = 0; j < 8; ++j) {
            if (m[j]) cb[base + (unsigned int)__popcll(mask[j] & lt)] = kk[j];
            base += (unsigned int)__popcll(mask[j]);
        }
    }
}

// ---------------- T2 v3: count-hist radix + direct sum. ~10 barriers, zero fp LDS atomics ----
__global__ __launch_bounds__(1024) void k_fin2(
    const unsigned int* __restrict__ scal,
    const unsigned int* __restrict__ l1c, const float* __restrict__ l1s,
    const unsigned int* __restrict__ cbuf, float* __restrict__ out)
{
    __shared__ unsigned int hc[4096];
    __shared__ unsigned int s_sel[2];
    __shared__ float spart[16];

    const int b = blockIdx.x;
    const int tid = threadIdx.x;
    const unsigned int np = scal[b * 16];
    const unsigned int k = calck(scal, b);
    float s_top = 0.0f;

    if (k > 0) {   // block-uniform
        unsigned int c1, cab1; float sab1;
        wave_sel256(l1c + b * 256, l1s + b * 256, k, &c1, &cab1, &sab1);   // redundant per wave
        const unsigned int t2 = k - cab1;
        unsigned int ns[8];
#pragma unroll
        for (int s = 0; s < 8; ++s) ns[s] = scal[b * 16 + 8 + s];

        // --- pass A: count hist of bits [23:12] (all cbuf keys have top byte == c1) ---
        for (int j = tid; j < 4096; j += 1024) hc[j] = 0u;
        __syncthreads();
#pragma unroll 1
        for (int s = 0; s < 8; ++s) {
            const unsigned int n2 = ns[s];
            const unsigned int* cb = cbuf + (size_t)b * IMGCAP + s * SEGCAP;
            for (unsigned int base = 0; base < n2; base += 4096) {
                const unsigned int i0 = base + tid, i1 = i0 + 1024, i2 = i0 + 2048, i3 = i0 + 3072;
                const unsigned int k0 = (i0 < n2) ? cb[i0] : 0u;
                const unsigned int k1 = (i1 < n2) ? cb[i1] : 0u;
                const unsigned int k2 = (i2 < n2) ? cb[i2] : 0u;
                const unsigned int k3 = (i3 < n2) ? cb[i3] : 0u;
                if (i0 < n2) atomicAdd(&hc[(k0 >> 12) & 0xfffu], 1u);
                if (i1 < n2) atomicAdd(&hc[(k1 >> 12) & 0xfffu], 1u);
                if (i2 < n2) atomicAdd(&hc[(k2 >> 12) & 0xfffu], 1u);
                if (i3 < n2) atomicAdd(&hc[(k3 >> 12) & 0xfffu], 1u);
            }
        }
        __syncthreads();
        if (tid < 64) {   // wave 0 only: barrier-free select, LDS broadcast
            unsigned int c2w, cab2w;
            wave_sel4096_cnt(hc, t2, &c2w, &cab2w);
            if (tid == 0) { s_sel[0] = c2w; s_sel[1] = cab2w; }
        }
        __syncthreads();
        const unsigned int c2 = s_sel[0];
        const unsigned int t3 = t2 - s_sel[1];
        __syncthreads();   // all waves have read s_sel/hc before reuse

        // --- pass B: count hist of low 12 bits for keys with mid-12 == c2 ---
        for (int j = tid; j < 4096; j += 1024) hc[j] = 0u;
        __syncthreads();
#pragma unroll 1
        for (int s = 0; s < 8; ++s) {
            const unsigned int n2 = ns[s];
            const unsigned int* cb = cbuf + (size_t)b * IMGCAP + s * SEGCAP;
            for (unsigned int base = 0; base < n2; base += 4096) {
                const unsigned int i0 = base + tid, i1 = i0 + 1024, i2 = i0 + 2048, i3 = i0 + 3072;
                const unsigned int k0 = (i0 < n2) ? cb[i0] : 0u;
                const unsigned int k1 = (i1 < n2) ? cb[i1] : 0u;
                const unsigned int k2 = (i2 < n2) ? cb[i2] : 0u;
                const unsigned int k3 = (i3 < n2) ? cb[i3] : 0u;
                if (i0 < n2 && ((k0 >> 12) & 0xfffu) == c2) atomicAdd(&hc[k0 & 0xfffu], 1u);
                if (i1 < n2 && ((k1 >> 12) & 0xfffu) == c2) atomicAdd(&hc[k1 & 0xfffu], 1u);
                if (i2 < n2 && ((k2 >> 12) & 0xfffu) == c2) atomicAdd(&hc[k2 & 0xfffu], 1u);
                if (i3 < n2 && ((k3 >> 12) & 0xfffu) == c2) atomicAdd(&hc[k3 & 0xfffu], 1u);
            }
        }
        __syncthreads();
        if (tid < 64) {
            unsigned int c3w, cab3w;
            wave_sel4096_cnt(hc, t3, &c3w, &cab3w);
            if (tid == 0) { s_sel[0] = c3w; s_sel[1] = cab3w; }
        }
        __syncthreads();
        const unsigned int keyv = (c1 << 24) | (c2 << 12) | s_sel[0];
        const unsigned int rem = t3 - s_sel[1];   // exact ties at threshold
        const float v = key2f(keyv);

        // --- pass C: direct sum of keys strictly above keyv (no atomics) ---
        float ls = 0.0f;
#pragma unroll 1
        for (int s = 0; s < 8; ++s) {
            const unsigned int n2 = ns[s];
            const unsigned int* cb = cbuf + (size_t)b * IMGCAP + s * SEGCAP;
            for (unsigned int base = 0; base < n2; base += 4096) {
                const unsigned int i0 = base + tid, i1 = i0 + 1024, i2 = i0 + 2048, i3 = i0 + 3072;
                const unsigned int k0 = (i0 < n2) ? cb[i0] : 0u;
                const unsigned int k1 = (i1 < n2) ? cb[i1] : 0u;
                const unsigned int k2 = (i2 < n2) ? cb[i2] : 0u;
                const unsigned int k3 = (i3 < n2) ? cb[i3] : 0u;
                if (k0 > keyv) ls += key2f(k0);   // key 0 never > keyv
                if (k1 > keyv) ls += key2f(k1);
                if (k2 > keyv) ls += key2f(k2);
                if (k3 > keyv) ls += key2f(k3);
            }
        }
        for (int off = 32; off; off >>= 1) ls += __shfl_xor(ls, off);
        if ((tid & 63) == 0) spart[tid >> 6] = ls;
        __syncthreads();
        if (tid == 0) {
            float S = 0.0f;
#pragma unroll
            for (int w = 0; w < 16; ++w) S += spart[w];
            s_top = sab1 + S + (float)rem * v;
        }
    }

    if (tid == 0) {
        float cls_loss = 0.0f, box_loss = 0.0f;
        if (np > 0) {
            const float* fsc = (const float*)(scal + b * 16);
            const float pos_mean = fsc[2] / (float)np;
            const float neg_mean = s_top / (float)((k > 0) ? k : 1u);
            cls_loss = pos_mean + neg_mean;
            box_loss = fsc[3] / (float)(4u * np);
        }
        out[b] = cls_loss;
        out[NB + b] = box_loss;
    }
}

extern "C" void kernel_launch(void* const* d_in, const int* in_sizes, int n_in,
                              void* d_out, int out_size, void* d_ws, size_t ws_size,
                              hipStream_t stream) {
    const float* cls     = (const float*)d_in[0];   // (B, A, 2)
    const float* reg     = (const float*)d_in[1];   // (B, A, 4)
    const float* anchors = (const float*)d_in[2];   // (1, A, 4)
    const float* ann     = (const float*)d_in[3];   // (B, M, 4)
    unsigned int* ws = (unsigned int*)d_ws;
    unsigned int* scal = ws + O_SCAL;
    unsigned int* l1c  = ws + O_L1C;   float* l1s = (float*)(ws + O_L1S);
    unsigned int* keys = ws + O_KEYS;
    unsigned int* cbuf = ws + O_CBUF;
    (void)in_sizes; (void)n_in; (void)out_size; (void)ws_size;

    hipMemsetAsync(d_ws, 0, (size_t)N_ZERO * 4, stream);
    k_main<<<dim3(CPB, NB),  256,  0, stream>>>(cls, reg, anchors, ann, scal, l1c, l1s, keys);
    k_h2c <<<dim3(NB * SPB), 256,  0, stream>>>(keys, scal, l1c, l1s, cbuf);
    k_fin2<<<dim3(NB),       1024, 0, stream>>>(scal, l1c, l1s, cbuf, (float*)d_out);
}